// Round 5
// baseline (65.063 us; speedup 1.0000x reference)
//
#include <hip/hip_runtime.h>

#define BB 4
#define CC 64
#define HH 128
#define WW 128
#define OO 64
#define HWs (HH*WW)

typedef _Float16 f16;
typedef _Float16 f16x8 __attribute__((ext_vector_type(8)));
typedef float f32x4 __attribute__((ext_vector_type(4)));

// xt layout: [b][y][x][64c] f16 (NHWC)
__device__ __forceinline__ size_t xt_idx(int b, int y, int x) {
    return (((size_t)b * HH + y) * WW + x) * CC;
}

// ---------- fused prep: x transpose (NCHW f32 -> NHWC f16) + weight packing ----------
__global__ __launch_bounds__(256) void prep_all(const float* __restrict__ x,
                                                const float* __restrict__ offw,
                                                const float* __restrict__ dw,
                                                f16* __restrict__ xt,
                                                f16* __restrict__ wA_off,
                                                f16* __restrict__ wA_def) {
    const int bid = blockIdx.x;
    const int tid = threadIdx.x;
    if (bid < 512) {
        const int b = bid >> 7, y = bid & 127;
        const int px = tid & 127, half = tid >> 7;
        const float* src = x + (size_t)b * CC * HWs + (size_t)half * 32 * HWs + y * WW + px;
        f16* dst = xt + xt_idx(b, y, px) + half * 32;
        #pragma unroll
        for (int cg = 0; cg < 4; ++cg) {
            f16x8 v;
            #pragma unroll
            for (int j = 0; j < 8; ++j)
                v[j] = (f16)src[(size_t)(cg * 8 + j) * HWs];
            *(f16x8*)(dst + cg * 8) = v;
        }
    } else {
        const int t = (bid - 512) * 256 + tid;
        const int l = t & 63;
        const int idx = t >> 6;
        f16x8 v;
        if (idx < 36) {
            const int mt = idx & 1, ks = idx >> 1;
            const int o = mt * 16 + (l & 15);
            const int tap = ks >> 1, ky = tap / 3, kx = tap % 3;
            #pragma unroll
            for (int i = 0; i < 8; ++i) {
                const int c = (ks & 1) * 32 + (l >> 4) * 8 + i;
                v[i] = (o < 18) ? (f16)offw[((o * CC + c) * 3 + ky) * 3 + kx] : (f16)0.f;
            }
            *(f16x8*)(wA_off + (size_t)(idx * 64 + l) * 8) = v;
        } else if (idx < 108) {
            const int id2 = idx - 36;
            const int mt = id2 & 3, ks = (id2 >> 2) & 1, tap = id2 >> 3;
            const int o = mt * 16 + (l & 15);
            #pragma unroll
            for (int i = 0; i < 8; ++i) {
                const int c = ks * 32 + (l >> 4) * 8 + i;
                v[i] = (f16)dw[(size_t)(o * CC + c) * 9 + tap];
            }
            *(f16x8*)(wA_def + (size_t)(id2 * 64 + l) * 8) = v;
        }
    }
}

__device__ __forceinline__ f16x8 combine4(f16x8 p00, f16x8 p01, f16x8 p10, f16x8 p11,
                                          float w00, float w01, float w10, float w11) {
    const f16 h00 = (f16)w00, h01 = (f16)w01, h10 = (f16)w10, h11 = (f16)w11;
    const f16x8 W00 = {h00,h00,h00,h00,h00,h00,h00,h00};
    const f16x8 W01 = {h01,h01,h01,h01,h01,h01,h01,h01};
    const f16x8 W10 = {h10,h10,h10,h10,h10,h10,h10,h10};
    const f16x8 W11 = {h11,h11,h11,h11,h11,h11,h11,h11};
    return p00 * W00 + p01 * W01 + p10 * W10 + p11 * W11;
}

// ---------- main: single 5-row full-c window; phase1 + both phase2 c-passes ----------
__global__ __launch_bounds__(256, 3) void deform_mfma(
    const f16* __restrict__ xt,
    const f16* __restrict__ wA_off,
    const float* __restrict__ offb,
    const f16* __restrict__ wA_def,
    const float* __restrict__ dbias,
    float* __restrict__ out)
{
    // [5 rows][68 px][8 chunks of 16B (8 f16 ch)], chunk index XOR-swizzled
    __shared__ __align__(16) char win[5 * 68 * 8 * 16];   // 43520 B
    __shared__ float offs[18][64];

    const int tid = threadIdx.x;
    const int bid0 = blockIdx.x;
    const int bid = (bid0 & 7) * 128 + (bid0 >> 3);   // XCD-aware swizzle (1024 % 8 == 0)
    const int b = bid >> 8, row = (bid >> 1) & 127, px0 = (bid & 1) * 64;
    const int w = tid >> 6, l = tid & 63;
    const int pxs = l & 15, pxl = w * 16 + pxs, gpx = px0 + pxl, cg = l >> 4;

    // ---- stage: rows row-2..row+2, x in [px0-2, px0+65], all 64 c; coalesced 128B/8 lanes ----
    for (int i = tid; i < 5 * 68 * 8; i += 256) {
        const int s = i / 544, rem = i - s * 544;
        const int xw = rem >> 3, ch8 = rem & 7;
        const int gy = row - 2 + s, gx = px0 - 2 + xw;
        f16x8 v = {};
        if (gy >= 0 && gy < HH && gx >= 0 && gx < WW)
            v = *(const f16x8*)(xt + xt_idx(b, gy, gx) + ch8 * 8);
        *(f16x8*)(win + ((s * 68 + xw) * 8 + (ch8 ^ ((xw + s) & 7))) * 16) = v;
    }
    __syncthreads();

    // ---- phase 1: offset conv [18(pad32) x 64px x 576] from window rows 1..3 ----
    {
        f32x4 oa0 = {0,0,0,0}, oa1 = {0,0,0,0};
        #pragma unroll
        for (int ks = 0; ks < 18; ++ks) {
            const int tap = ks >> 1, chalf = ks & 1;
            const int ky = tap / 3, kx = tap - ky * 3;
            const int s = 1 + ky;
            const int xw = pxl + 1 + kx;
            const int ch8 = chalf * 4 + cg;
            const int byte = ((s * 68 + xw) * 8 + (ch8 ^ ((xw + s) & 7))) * 16;
            const f16x8 bf = *(const f16x8*)(win + byte);
            const f16x8 a0 = *(const f16x8*)(wA_off + (size_t)((ks * 2 + 0) * 64 + l) * 8);
            const f16x8 a1 = *(const f16x8*)(wA_off + (size_t)((ks * 2 + 1) * 64 + l) * 8);
            oa0 = __builtin_amdgcn_mfma_f32_16x16x32_f16(a0, bf, oa0, 0, 0, 0);
            oa1 = __builtin_amdgcn_mfma_f32_16x16x32_f16(a1, bf, oa1, 0, 0, 0);
        }
        #pragma unroll
        for (int reg = 0; reg < 4; ++reg) {
            const int o0 = cg * 4 + reg;
            offs[o0][pxl] = oa0[reg] + offb[o0];
            const int o1 = o0 + 16;
            if (o1 < 18) offs[o1][pxl] = oa1[reg] + offb[o1];
        }
    }
    __syncthreads();   // offs ready; win is read-only from here (no restage)

    f32x4 acc0 = {0,0,0,0}, acc1 = {0,0,0,0}, acc2 = {0,0,0,0}, acc3 = {0,0,0,0};

    // ---- phase 2: 9 taps x 2 c-passes, gathers from the SAME window ----
    #pragma unroll
    for (int cpass = 0; cpass < 2; ++cpass) {
        #pragma unroll
        for (int t = 0; t < 9; ++t) {
            const int ky = t / 3, kx = t - ky * 3;
            const float dy = offs[2 * t][pxl], dx = offs[2 * t + 1][pxl];
            const float py  = (float)(row - 1 + ky) + dy;
            const float pxf = (float)(gpx - 1 + kx) + dx;
            const float y0f = floorf(py), x0f = floorf(pxf);
            const float wy = py - y0f, wx = pxf - x0f;
            const int y0 = (int)y0f, x0 = (int)x0f;
            const int y1 = y0 + 1, x1 = x0 + 1;
            const bool vy0 = (y0 >= 0) & (y0 < HH), vy1 = (y1 >= 0) & (y1 < HH);
            const bool vx0 = (x0 >= 0) & (x0 < WW), vx1 = (x1 >= 0) & (x1 < WW);
            const float w00 = (1.f - wy) * (1.f - wx) * (float)(vy0 & vx0);
            const float w01 = (1.f - wy) * wx         * (float)(vy0 & vx1);
            const float w10 = wy * (1.f - wx)         * (float)(vy1 & vx0);
            const float w11 = wy * wx                 * (float)(vy1 & vx1);
            const int cy0 = min(max(y0, 0), HH - 1), cy1 = min(max(y1, 0), HH - 1);
            const int cx0 = min(max(x0, 0), WW - 1), cx1 = min(max(x1, 0), WW - 1);
            const int s0 = cy0 - (row - 2), s1 = cy1 - (row - 2);
            const int u0 = cx0 - (px0 - 2), u1 = cx1 - (px0 - 2);
            const int ok = (s0 >= 0) & (s0 < 5) & (s1 >= 0) & (s1 < 5) &
                           (u0 >= 0) & (u0 < 68) & (u1 >= 0) & (u1 < 68);
            const int ch8 = cpass * 4 + cg;
            f16x8 bf;
            if (__all(ok)) {
                const int o00 = ((s0 * 68 + u0) * 8 + (ch8 ^ ((u0 + s0) & 7))) * 16;
                const int o01 = ((s0 * 68 + u1) * 8 + (ch8 ^ ((u1 + s0) & 7))) * 16;
                const int o10 = ((s1 * 68 + u0) * 8 + (ch8 ^ ((u0 + s1) & 7))) * 16;
                const int o11 = ((s1 * 68 + u1) * 8 + (ch8 ^ ((u1 + s1) & 7))) * 16;
                const f16x8 p00 = *(const f16x8*)(win + o00);
                const f16x8 p01 = *(const f16x8*)(win + o01);
                const f16x8 p10 = *(const f16x8*)(win + o10);
                const f16x8 p11 = *(const f16x8*)(win + o11);
                bf = combine4(p00, p01, p10, p11, w00, w01, w10, w11);
            } else {
                const f16x8 p00 = *(const f16x8*)(xt + xt_idx(b, cy0, cx0) + ch8 * 8);
                const f16x8 p01 = *(const f16x8*)(xt + xt_idx(b, cy0, cx1) + ch8 * 8);
                const f16x8 p10 = *(const f16x8*)(xt + xt_idx(b, cy1, cx0) + ch8 * 8);
                const f16x8 p11 = *(const f16x8*)(xt + xt_idx(b, cy1, cx1) + ch8 * 8);
                bf = combine4(p00, p01, p10, p11, w00, w01, w10, w11);
            }
            const f16* wa = wA_def + (size_t)(((t * 2 + cpass) * 4) * 64 + l) * 8;
            const f16x8 A0 = *(const f16x8*)(wa + (size_t)0 * 64 * 8);
            const f16x8 A1 = *(const f16x8*)(wa + (size_t)1 * 64 * 8);
            const f16x8 A2 = *(const f16x8*)(wa + (size_t)2 * 64 * 8);
            const f16x8 A3 = *(const f16x8*)(wa + (size_t)3 * 64 * 8);
            acc0 = __builtin_amdgcn_mfma_f32_16x16x32_f16(A0, bf, acc0, 0, 0, 0);
            acc1 = __builtin_amdgcn_mfma_f32_16x16x32_f16(A1, bf, acc1, 0, 0, 0);
            acc2 = __builtin_amdgcn_mfma_f32_16x16x32_f16(A2, bf, acc2, 0, 0, 0);
            acc3 = __builtin_amdgcn_mfma_f32_16x16x32_f16(A3, bf, acc3, 0, 0, 0);
        }
    }

    // ---- epilogue ----
    #pragma unroll
    for (int mt = 0; mt < 4; ++mt) {
        const f32x4 a = (mt == 0) ? acc0 : (mt == 1) ? acc1 : (mt == 2) ? acc2 : acc3;
        #pragma unroll
        for (int reg = 0; reg < 4; ++reg) {
            const int o = mt * 16 + cg * 4 + reg;
            out[(((size_t)b * OO + o) * HH + row) * WW + gpx] = a[reg] + dbias[o];
        }
    }
}

extern "C" void kernel_launch(void* const* d_in, const int* in_sizes, int n_in,
                              void* d_out, int out_size, void* d_ws, size_t ws_size,
                              hipStream_t stream) {
    const float* x     = (const float*)d_in[0];
    const float* offw  = (const float*)d_in[1];
    const float* offb  = (const float*)d_in[2];
    const float* dw    = (const float*)d_in[3];
    const float* dbias = (const float*)d_in[4];
    float* out = (float*)d_out;

    const size_t XT_BYTES    = (size_t)BB * HH * WW * CC * sizeof(f16);   // 8 MiB
    const size_t WAOFF_BYTES = 36 * 64 * 8 * sizeof(f16);

    f16* xt     = (f16*)d_ws;
    f16* wa_off = (f16*)((char*)d_ws + XT_BYTES);
    f16* wa_def = (f16*)((char*)d_ws + XT_BYTES + WAOFF_BYTES);
    (void)ws_size; (void)in_sizes; (void)n_in; (void)out_size;

    prep_all<<<512 + 27, 256, 0, stream>>>(x, offw, dw, xt, wa_off, wa_def);
    deform_mfma<<<BB * HH * 2, 256, 0, stream>>>(xt, wa_off, offb, wa_def, dbias, out);
}

// Round 6
// 40.838 us; speedup vs baseline: 1.5932x; 1.5932x over previous
//
#include <hip/hip_runtime.h>

#define BB 4
#define CC 64
#define HH 128
#define WW 128
#define OO 64
#define HWs (HH*WW)

typedef _Float16 f16;
typedef _Float16 f16x8 __attribute__((ext_vector_type(8)));
typedef float f32x4 __attribute__((ext_vector_type(4)));

// xt layout: [b][y][x][64c] f16 (NHWC)
__device__ __forceinline__ size_t xt_idx(int b, int y, int x) {
    return (((size_t)b * HH + y) * WW + x) * CC;
}

// ---------- fused prep: x transpose (NCHW f32 -> NHWC f16) + weight packing ----------
__global__ __launch_bounds__(256) void prep_all(const float* __restrict__ x,
                                                const float* __restrict__ offw,
                                                const float* __restrict__ dw,
                                                f16* __restrict__ xt,
                                                f16* __restrict__ wA_off,
                                                f16* __restrict__ wA_def) {
    const int bid = blockIdx.x;
    const int tid = threadIdx.x;
    if (bid < 512) {
        const int b = bid >> 7, y = bid & 127;
        const int px = tid & 127, half = tid >> 7;
        const float* src = x + (size_t)b * CC * HWs + (size_t)half * 32 * HWs + y * WW + px;
        f16* dst = xt + xt_idx(b, y, px) + half * 32;
        #pragma unroll
        for (int cg = 0; cg < 4; ++cg) {
            f16x8 v;
            #pragma unroll
            for (int j = 0; j < 8; ++j)
                v[j] = (f16)src[(size_t)(cg * 8 + j) * HWs];
            *(f16x8*)(dst + cg * 8) = v;
        }
    } else {
        const int t = (bid - 512) * 256 + tid;
        const int l = t & 63;
        const int idx = t >> 6;
        f16x8 v;
        if (idx < 36) {
            const int mt = idx & 1, ks = idx >> 1;
            const int o = mt * 16 + (l & 15);
            const int tap = ks >> 1, ky = tap / 3, kx = tap % 3;
            #pragma unroll
            for (int i = 0; i < 8; ++i) {
                const int c = (ks & 1) * 32 + (l >> 4) * 8 + i;
                v[i] = (o < 18) ? (f16)offw[((o * CC + c) * 3 + ky) * 3 + kx] : (f16)0.f;
            }
            *(f16x8*)(wA_off + (size_t)(idx * 64 + l) * 8) = v;
        } else if (idx < 108) {
            const int id2 = idx - 36;
            const int mt = id2 & 3, ks = (id2 >> 2) & 1, tap = id2 >> 3;
            const int o = mt * 16 + (l & 15);
            #pragma unroll
            for (int i = 0; i < 8; ++i) {
                const int c = ks * 32 + (l >> 4) * 8 + i;
                v[i] = (f16)dw[(size_t)(o * CC + c) * 9 + tap];
            }
            *(f16x8*)(wA_def + (size_t)(id2 * 64 + l) * 8) = v;
        }
    }
}

__device__ __forceinline__ f16x8 combine4(f16x8 p00, f16x8 p01, f16x8 p10, f16x8 p11,
                                          float w00, float w01, float w10, float w11) {
    const f16 h00 = (f16)w00, h01 = (f16)w01, h10 = (f16)w10, h11 = (f16)w11;
    const f16x8 W00 = {h00,h00,h00,h00,h00,h00,h00,h00};
    const f16x8 W01 = {h01,h01,h01,h01,h01,h01,h01,h01};
    const f16x8 W10 = {h10,h10,h10,h10,h10,h10,h10,h10};
    const f16x8 W11 = {h11,h11,h11,h11,h11,h11,h11,h11};
    return p00 * W00 + p01 * W01 + p10 * W10 + p11 * W11;
}

// ---------- main: single 5-row full-c window; phase1 + phase2 (tap-outer) ----------
__global__ __launch_bounds__(256, 2) void deform_mfma(
    const f16* __restrict__ xt,
    const f16* __restrict__ wA_off,
    const float* __restrict__ offb,
    const f16* __restrict__ wA_def,
    const float* __restrict__ dbias,
    float* __restrict__ out)
{
    // [5 rows][68 px][8 chunks of 16B (8 f16 ch)], chunk index XOR-swizzled
    __shared__ __align__(16) char win[5 * 68 * 8 * 16];   // 43520 B
    __shared__ float offs[18][64];

    const int tid = threadIdx.x;
    const int bid0 = blockIdx.x;
    const int bid = (bid0 & 7) * 128 + (bid0 >> 3);   // XCD-aware swizzle (1024 % 8 == 0)
    const int b = bid >> 8, row = (bid >> 1) & 127, px0 = (bid & 1) * 64;
    const int w = tid >> 6, l = tid & 63;
    const int pxs = l & 15, pxl = w * 16 + pxs, gpx = px0 + pxl, cg = l >> 4;

    // ---- stage: rows row-2..row+2, x in [px0-2, px0+65], all 64 c; coalesced ----
    for (int i = tid; i < 5 * 68 * 8; i += 256) {
        const int s = i / 544, rem = i - s * 544;
        const int xw = rem >> 3, ch8 = rem & 7;
        const int gy = row - 2 + s, gx = px0 - 2 + xw;
        f16x8 v = {};
        if (gy >= 0 && gy < HH && gx >= 0 && gx < WW)
            v = *(const f16x8*)(xt + xt_idx(b, gy, gx) + ch8 * 8);
        *(f16x8*)(win + ((s * 68 + xw) * 8 + (ch8 ^ ((xw + s) & 7))) * 16) = v;
    }
    __syncthreads();

    // ---- phase 1: offset conv [18(pad32) x 64px x 576] from window rows 1..3 ----
    {
        f32x4 oa0 = {0,0,0,0}, oa1 = {0,0,0,0};
        #pragma unroll
        for (int ks = 0; ks < 18; ++ks) {
            const int tap = ks >> 1, chalf = ks & 1;
            const int ky = tap / 3, kx = tap - ky * 3;
            const int s = 1 + ky;
            const int xw = pxl + 1 + kx;
            const int ch8 = chalf * 4 + cg;
            const int byte = ((s * 68 + xw) * 8 + (ch8 ^ ((xw + s) & 7))) * 16;
            const f16x8 bf = *(const f16x8*)(win + byte);
            const f16x8 a0 = *(const f16x8*)(wA_off + (size_t)((ks * 2 + 0) * 64 + l) * 8);
            const f16x8 a1 = *(const f16x8*)(wA_off + (size_t)((ks * 2 + 1) * 64 + l) * 8);
            oa0 = __builtin_amdgcn_mfma_f32_16x16x32_f16(a0, bf, oa0, 0, 0, 0);
            oa1 = __builtin_amdgcn_mfma_f32_16x16x32_f16(a1, bf, oa1, 0, 0, 0);
        }
        #pragma unroll
        for (int reg = 0; reg < 4; ++reg) {
            const int o0 = cg * 4 + reg;
            offs[o0][pxl] = oa0[reg] + offb[o0];
            const int o1 = o0 + 16;
            if (o1 < 18) offs[o1][pxl] = oa1[reg] + offb[o1];
        }
    }
    __syncthreads();   // offs ready; win is read-only from here (no restage)

    f32x4 acc0 = {0,0,0,0}, acc1 = {0,0,0,0}, acc2 = {0,0,0,0}, acc3 = {0,0,0,0};

    // ---- phase 2: 9 taps (params computed ONCE) x 2 c-passes from the SAME window ----
    #pragma unroll
    for (int t = 0; t < 9; ++t) {
        const int ky = t / 3, kx = t - ky * 3;
        const float dy = offs[2 * t][pxl], dx = offs[2 * t + 1][pxl];
        const float py  = (float)(row - 1 + ky) + dy;
        const float pxf = (float)(gpx - 1 + kx) + dx;
        const float y0f = floorf(py), x0f = floorf(pxf);
        const float wy = py - y0f, wx = pxf - x0f;
        const int y0 = (int)y0f, x0 = (int)x0f;
        const int y1 = y0 + 1, x1 = x0 + 1;
        const bool vy0 = (y0 >= 0) & (y0 < HH), vy1 = (y1 >= 0) & (y1 < HH);
        const bool vx0 = (x0 >= 0) & (x0 < WW), vx1 = (x1 >= 0) & (x1 < WW);
        const float w00 = (1.f - wy) * (1.f - wx) * (float)(vy0 & vx0);
        const float w01 = (1.f - wy) * wx         * (float)(vy0 & vx1);
        const float w10 = wy * (1.f - wx)         * (float)(vy1 & vx0);
        const float w11 = wy * wx                 * (float)(vy1 & vx1);
        const int cy0 = min(max(y0, 0), HH - 1), cy1 = min(max(y1, 0), HH - 1);
        const int cx0 = min(max(x0, 0), WW - 1), cx1 = min(max(x1, 0), WW - 1);
        const int s0 = cy0 - (row - 2), s1 = cy1 - (row - 2);
        const int u0 = cx0 - (px0 - 2), u1 = cx1 - (px0 - 2);
        const int ok = (s0 >= 0) & (s0 < 5) & (s1 >= 0) & (s1 < 5) &
                       (u0 >= 0) & (u0 < 68) & (u1 >= 0) & (u1 < 68);
        const int all_ok = __all(ok);
        // chunk-group bases and swizzle keys (ch8 varies per cpass)
        const int b00 = (s0 * 68 + u0) * 8, k00 = (u0 + s0) & 7;
        const int b01 = (s0 * 68 + u1) * 8, k01 = (u1 + s0) & 7;
        const int b10 = (s1 * 68 + u0) * 8, k10 = (u0 + s1) & 7;
        const int b11 = (s1 * 68 + u1) * 8, k11 = (u1 + s1) & 7;

        #pragma unroll
        for (int cpass = 0; cpass < 2; ++cpass) {
            const int ch8 = cpass * 4 + cg;
            f16x8 bf;
            if (all_ok) {
                const f16x8 p00 = *(const f16x8*)(win + (b00 + (ch8 ^ k00)) * 16);
                const f16x8 p01 = *(const f16x8*)(win + (b01 + (ch8 ^ k01)) * 16);
                const f16x8 p10 = *(const f16x8*)(win + (b10 + (ch8 ^ k10)) * 16);
                const f16x8 p11 = *(const f16x8*)(win + (b11 + (ch8 ^ k11)) * 16);
                bf = combine4(p00, p01, p10, p11, w00, w01, w10, w11);
            } else {
                const f16x8 p00 = *(const f16x8*)(xt + xt_idx(b, cy0, cx0) + ch8 * 8);
                const f16x8 p01 = *(const f16x8*)(xt + xt_idx(b, cy0, cx1) + ch8 * 8);
                const f16x8 p10 = *(const f16x8*)(xt + xt_idx(b, cy1, cx0) + ch8 * 8);
                const f16x8 p11 = *(const f16x8*)(xt + xt_idx(b, cy1, cx1) + ch8 * 8);
                bf = combine4(p00, p01, p10, p11, w00, w01, w10, w11);
            }
            const f16* wa = wA_def + (size_t)(((t * 2 + cpass) * 4) * 64 + l) * 8;
            const f16x8 A0 = *(const f16x8*)(wa + (size_t)0 * 64 * 8);
            const f16x8 A1 = *(const f16x8*)(wa + (size_t)1 * 64 * 8);
            const f16x8 A2 = *(const f16x8*)(wa + (size_t)2 * 64 * 8);
            const f16x8 A3 = *(const f16x8*)(wa + (size_t)3 * 64 * 8);
            acc0 = __builtin_amdgcn_mfma_f32_16x16x32_f16(A0, bf, acc0, 0, 0, 0);
            acc1 = __builtin_amdgcn_mfma_f32_16x16x32_f16(A1, bf, acc1, 0, 0, 0);
            acc2 = __builtin_amdgcn_mfma_f32_16x16x32_f16(A2, bf, acc2, 0, 0, 0);
            acc3 = __builtin_amdgcn_mfma_f32_16x16x32_f16(A3, bf, acc3, 0, 0, 0);
        }
    }

    // ---- epilogue ----
    #pragma unroll
    for (int mt = 0; mt < 4; ++mt) {
        const f32x4 a = (mt == 0) ? acc0 : (mt == 1) ? acc1 : (mt == 2) ? acc2 : acc3;
        #pragma unroll
        for (int reg = 0; reg < 4; ++reg) {
            const int o = mt * 16 + cg * 4 + reg;
            out[(((size_t)b * OO + o) * HH + row) * WW + gpx] = a[reg] + dbias[o];
        }
    }
}

extern "C" void kernel_launch(void* const* d_in, const int* in_sizes, int n_in,
                              void* d_out, int out_size, void* d_ws, size_t ws_size,
                              hipStream_t stream) {
    const float* x     = (const float*)d_in[0];
    const float* offw  = (const float*)d_in[1];
    const float* offb  = (const float*)d_in[2];
    const float* dw    = (const float*)d_in[3];
    const float* dbias = (const float*)d_in[4];
    float* out = (float*)d_out;

    const size_t XT_BYTES    = (size_t)BB * HH * WW * CC * sizeof(f16);   // 8 MiB
    const size_t WAOFF_BYTES = 36 * 64 * 8 * sizeof(f16);

    f16* xt     = (f16*)d_ws;
    f16* wa_off = (f16*)((char*)d_ws + XT_BYTES);
    f16* wa_def = (f16*)((char*)d_ws + XT_BYTES + WAOFF_BYTES);
    (void)ws_size; (void)in_sizes; (void)n_in; (void)out_size;

    prep_all<<<512 + 27, 256, 0, stream>>>(x, offw, dw, xt, wa_off, wa_def);
    deform_mfma<<<BB * HH * 2, 256, 0, stream>>>(xt, wa_off, offb, wa_def, dbias, out);
}